// Round 6
// baseline (432.615 us; speedup 1.0000x reference)
//
#include <hip/hip_runtime.h>
#include <hip/hip_fp16.h>
#include <math.h>

constexpr int Lq = 8, Cq = 16, Hq = 240, Wq = 480, Rq = 8, MIDq = 8, SEM = 4;
constexpr int HWq = Hq * Wq;

__device__ __forceinline__ float sigmoidf_(float v) { return 1.0f / (1.0f + expf(-v)); }

struct alignas(16) h8 { __half v[8]; };

// conv1: x (L,16,H,W) -> silu -> f1 (L,8,H,W), 3x3 SAME zero-pad.
// 2 px/thread, 240 active threads, grid L*H -> 7680 waves (R5: 4px/120thr was
// occupancy-starved at 33%, VALUBusy 38%).
__global__ void k_conv1(const float* __restrict__ x, const float* __restrict__ w1,
                        const float* __restrict__ b1, float* __restrict__ f1) {
    int b = blockIdx.x;
    int l = b & 7, y = b >> 3;
    int t = threadIdx.x;
    if (t >= Wq / 2) return;
    int xi = t * 2;
    float acc[MIDq][2];
#pragma unroll
    for (int m = 0; m < MIDq; m++) {
        float bv = b1[m];
        acc[m][0] = bv; acc[m][1] = bv;
    }
#pragma unroll 1
    for (int ic = 0; ic < Cq; ic++) {
        const float* xin = x + (size_t)(l * Cq + ic) * HWq;
        const float* wrow = w1 + ic * 9;
#pragma unroll
        for (int r = 0; r < 3; r++) {
            int yy = y + r - 1;
            if (yy < 0 || yy >= Hq) continue;
            const float* rp = xin + yy * Wq;
            float2 mid = *(const float2*)(rp + xi);
            float lft = (xi > 0) ? rp[xi - 1] : 0.f;
            float rgt = (xi + 2 < Wq) ? rp[xi + 2] : 0.f;
            float in4[4] = {lft, mid.x, mid.y, rgt};
#pragma unroll
            for (int m = 0; m < MIDq; m++) {
                const float* wp = wrow + m * (Cq * 9) + r * 3;
                float w0 = wp[0], w1v = wp[1], w2 = wp[2];
#pragma unroll
                for (int o = 0; o < 2; o++)
                    acc[m][o] = fmaf(w0, in4[o],
                                fmaf(w1v, in4[o + 1],
                                fmaf(w2, in4[o + 2], acc[m][o])));
            }
        }
    }
    size_t rowoff = (size_t)y * Wq + xi;
#pragma unroll
    for (int m = 0; m < MIDq; m++) {
        float a0 = acc[m][0], a1 = acc[m][1];
        float2 v = {a0 * sigmoidf_(a0), a1 * sigmoidf_(a1)};
        *(float2*)(f1 + (size_t)(l * MIDq + m) * HWq + rowoff) = v;
    }
}

// conv2: f1 (L,8,H,W) -> f (L,2,H,W), 3x3 SAME zero-pad.
__global__ void k_conv2(const float* __restrict__ f1, const float* __restrict__ w2,
                        const float* __restrict__ b2, float* __restrict__ f) {
    int b = blockIdx.x;
    int l = b & 7, y = b >> 3;
    int t = threadIdx.x;
    if (t >= Wq / 4) return;
    int xi = t * 4;
    float acc[2][4];
#pragma unroll
    for (int m = 0; m < 2; m++) {
        float bv = b2[m];
#pragma unroll
        for (int o = 0; o < 4; o++) acc[m][o] = bv;
    }
#pragma unroll 1
    for (int ic = 0; ic < MIDq; ic++) {
        const float* fin = f1 + (size_t)(l * MIDq + ic) * HWq;
        const float* wrow = w2 + ic * 9;
#pragma unroll
        for (int r = 0; r < 3; r++) {
            int yy = y + r - 1;
            if (yy < 0 || yy >= Hq) continue;
            const float* rp = fin + yy * Wq;
            float4 mid = *(const float4*)(rp + xi);
            float lft = (xi > 0) ? rp[xi - 1] : 0.f;
            float rgt = (xi + 4 < Wq) ? rp[xi + 4] : 0.f;
            float in6[6] = {lft, mid.x, mid.y, mid.z, mid.w, rgt};
#pragma unroll
            for (int m = 0; m < 2; m++) {
                const float* wp = wrow + m * (MIDq * 9) + r * 3;
                float w0 = wp[0], w1v = wp[1], w2v = wp[2];
#pragma unroll
                for (int o = 0; o < 4; o++)
                    acc[m][o] = fmaf(w0, in6[o],
                                fmaf(w1v, in6[o + 1],
                                fmaf(w2v, in6[o + 2], acc[m][o])));
            }
        }
    }
    size_t rowoff = (size_t)y * Wq + xi;
#pragma unroll
    for (int m = 0; m < 2; m++) {
        float4 v = {acc[m][0], acc[m][1], acc[m][2], acc[m][3]};
        *(float4*)(f + (size_t)(l * 2 + m) * HWq + rowoff) = v;
    }
}

// sobel (wrap-x, edge-y) + metric + tanh -> flow (L,2,H,W)
__global__ void k_flow(const float* __restrict__ f, float* __restrict__ flow) {
    int idx = blockIdx.x * blockDim.x + threadIdx.x;
    if (idx >= Lq * HWq) return;
    int l = idx / HWq, rem = idx % HWq, y = rem / Wq, x = rem % Wq;
    const float* phi = f + (size_t)(l * 2 + 0) * HWq;
    const float* psi = f + (size_t)(l * 2 + 1) * HWq;
    float ph[3][3], ps[3][3];
#pragma unroll
    for (int i = 0; i < 3; i++) {
        int yy = y + i - 1;
        yy = yy < 0 ? 0 : (yy >= Hq ? Hq - 1 : yy);
#pragma unroll
        for (int j = 0; j < 3; j++) {
            int xx = x + j - 1;
            xx = (xx + Wq) % Wq;
            ph[i][j] = phi[yy * Wq + xx];
            ps[i][j] = psi[yy * Wq + xx];
        }
    }
    float gxp = (ph[0][2] - ph[0][0]) + 2.f * (ph[1][2] - ph[1][0]) + (ph[2][2] - ph[2][0]);
    float gyp = (ph[2][0] + 2.f * ph[2][1] + ph[2][2]) - (ph[0][0] + 2.f * ph[0][1] + ph[0][2]);
    float gxs = (ps[0][2] - ps[0][0]) + 2.f * (ps[1][2] - ps[1][0]) + (ps[2][2] - ps[2][0]);
    float gys = (ps[2][0] + 2.f * ps[2][1] + ps[2][2]) - (ps[0][0] + 2.f * ps[0][1] + ps[0][2]);
    float latf = (float)(-M_PI * 0.5 + (double)y * (M_PI / (double)(Hq - 1)));
    float metric = (float)(1.0 / (cos((double)latf) + 1e-6));
    float u = gxp * metric - gys;
    float v = gyp + gxs * metric;
    flow[(size_t)(l * 2 + 0) * HWq + rem] = tanhf(u);
    flow[(size_t)(l * 2 + 1) * HWq + rem] = tanhf(v);
}

// one-time: h0 (C,H,W,R) fp32 -> hpack (H,W,C,R) fp16
__global__ void k_pack(const float* __restrict__ h0, h8* __restrict__ hp) {
    int px = blockIdx.x * 256 + threadIdx.x;   // 0..HW-1
    const float4* h4 = (const float4*)h0;
#pragma unroll 1
    for (int c = 0; c < Cq; c++) {
        float4 a = h4[(size_t)(c * HWq + px) * 2];
        float4 b = h4[(size_t)(c * HWq + px) * 2 + 1];
        h8 o;
        o.v[0] = __float2half(a.x); o.v[1] = __float2half(a.y);
        o.v[2] = __float2half(a.z); o.v[3] = __float2half(a.w);
        o.v[4] = __float2half(b.x); o.v[5] = __float2half(b.y);
        o.v[6] = __float2half(b.z); o.v[7] = __float2half(b.w);
        hp[(size_t)px * Cq + c] = o;
    }
}

// warp (bilinear, border clamp) + add x_t + per-channel mean over R.
// h layout (H,W,C,R) fp16: all 16 channels share sample coords, so the 4
// corners are 4 contiguous 256B blocks -> L1-resident across the c-loop.
// 4 threads/px (4 channels each), 64 px/block, grid 1800 (7200 waves).
__global__ void k_warp(const h8* __restrict__ hin, h8* __restrict__ hout,
                       const float* __restrict__ flow_l, const float* __restrict__ xl,
                       const float* __restrict__ listT, int l,
                       float* __restrict__ xf) {
    int tid = threadIdx.x;
    int px = blockIdx.x * 64 + (tid >> 2);
    int csub = tid & 3;
    int y = px / Wq, x = px % Wq;
    float dt = listT[l];
    float u = flow_l[px];
    float v = flow_l[HWq + px];
    float gxn = x * (2.0f / (Wq - 1)) - 1.0f;
    float gyn = y * (2.0f / (Hq - 1)) - 1.0f;
    float gx = gxn - u * dt;
    float gy = gyn - v * dt;
    float xp = (gx + 1.0f) * (Wq * 0.5f) - 0.5f;
    float yp = (gy + 1.0f) * (Hq * 0.5f) - 0.5f;
    xp = fminf(fmaxf(xp, 0.0f), (float)(Wq - 1));
    yp = fminf(fmaxf(yp, 0.0f), (float)(Hq - 1));
    float x0f = floorf(xp), y0f = floorf(yp);
    float wx = xp - x0f, wy = yp - y0f;
    int x0 = (int)x0f, y0 = (int)y0f;
    int x1 = min(x0 + 1, Wq - 1), y1 = min(y0 + 1, Hq - 1);
    int i00 = (y0 * Wq + x0) * Cq, i01 = (y0 * Wq + x1) * Cq;
    int i10 = (y1 * Wq + x0) * Cq, i11 = (y1 * Wq + x1) * Cq;
    float w00 = (1.f - wx) * (1.f - wy), w01 = wx * (1.f - wy);
    float w10 = (1.f - wx) * wy, w11 = wx * wy;
    int c0 = csub * 4;
    float m4[4];
#pragma unroll
    for (int cc = 0; cc < 4; cc++) {
        int c = c0 + cc;
        h8 A = hin[i00 + c], B = hin[i01 + c], C = hin[i10 + c], D = hin[i11 + c];
        float xt = xl[(size_t)c * HWq + px];
        float ssum = 0.f;
        h8 o;
#pragma unroll
        for (int k = 0; k < 8; k++) {
            float r = w00 * __half2float(A.v[k]) + w01 * __half2float(B.v[k]) +
                      w10 * __half2float(C.v[k]) + w11 * __half2float(D.v[k]);
            ssum += r;
            o.v[k] = __float2half(r + xt);
        }
        hout[(size_t)px * Cq + c] = o;
        m4[cc] = ssum * 0.125f + xt;
    }
    float4 mv = {m4[0], m4[1], m4[2], m4[3]};
    *(float4*)(xf + (size_t)px * Cq + c0) = mv;
}

// per row: rowsum from xf (regs) -> SE gate -> scale -> transposed store.
// block 512 (8 waves), grid H. Deterministic shfl+LDS reduction.
__global__ __launch_bounds__(512) void k_apply(const float* __restrict__ xf,
                        const float* __restrict__ sw1, const float* __restrict__ sb1,
                        const float* __restrict__ sw2, const float* __restrict__ sb2,
                        float* __restrict__ out_l) {
    int y = blockIdx.x;
    int t = threadIdx.x;
    int wave = t >> 6, lane = t & 63;
    bool act = t < Wq;
    int px = y * Wq + t;
    float vals[16];
    if (act) {
        const float4* p = (const float4*)(xf + (size_t)px * Cq);
        float4 a = p[0], b = p[1], c = p[2], d = p[3];
        vals[0] = a.x; vals[1] = a.y; vals[2] = a.z; vals[3] = a.w;
        vals[4] = b.x; vals[5] = b.y; vals[6] = b.z; vals[7] = b.w;
        vals[8] = c.x; vals[9] = c.y; vals[10] = c.z; vals[11] = c.w;
        vals[12] = d.x; vals[13] = d.y; vals[14] = d.z; vals[15] = d.w;
    } else {
#pragma unroll
        for (int i = 0; i < 16; i++) vals[i] = 0.f;
    }
    float s[16];
#pragma unroll
    for (int i = 0; i < 16; i++) s[i] = vals[i];
    for (int off = 32; off > 0; off >>= 1) {
#pragma unroll
        for (int i = 0; i < 16; i++) s[i] += __shfl_down(s[i], off, 64);
    }
    __shared__ float red[8][16];
    __shared__ float gates[16];
    if (lane == 0) {
#pragma unroll
        for (int i = 0; i < 16; i++) red[wave][i] = s[i];
    }
    __syncthreads();
    if (t < 16) {
        float ym[16];
#pragma unroll
        for (int i = 0; i < 16; i++) {
            float a = 0.f;
#pragma unroll
            for (int w = 0; w < 8; w++) a += red[w][i];
            ym[i] = a * (1.0f / Wq);
        }
        float z[SEM];
#pragma unroll
        for (int m = 0; m < SEM; m++) {
            float a = sb1[m];
#pragma unroll
            for (int i = 0; i < 16; i++) a = fmaf(sw1[m * Cq + i], ym[i], a);
            z[m] = a * sigmoidf_(a);
        }
        float a2 = sb2[t];
#pragma unroll
        for (int m = 0; m < SEM; m++) a2 = fmaf(sw2[t * SEM + m], z[m], a2);
        gates[t] = sigmoidf_(a2);
    }
    __syncthreads();
    if (act) {
#pragma unroll
        for (int c = 0; c < 16; c++)
            out_l[(size_t)c * HWq + px] = vals[c] * gates[c];
    }
}

extern "C" void kernel_launch(void* const* d_in, const int* in_sizes, int n_in,
                              void* d_out, int out_size, void* d_ws, size_t ws_size,
                              hipStream_t stream) {
    const float* x = (const float*)d_in[0];
    const float* h0 = (const float*)d_in[1];
    const float* listT = (const float*)d_in[2];
    const float* hw1 = (const float*)d_in[3];
    const float* hb1 = (const float*)d_in[4];
    const float* hw2 = (const float*)d_in[5];
    const float* hb2 = (const float*)d_in[6];
    const float* sw1 = (const float*)d_in[7];
    const float* sb1 = (const float*)d_in[8];
    const float* sw2 = (const float*)d_in[9];
    const float* sb2 = (const float*)d_in[10];
    float* out = (float*)d_out;
    char* ws = (char*)d_ws;

    size_t off = 0;
    float* flow = (float*)(ws + off); off += sizeof(float) * (size_t)Lq * 2 * HWq;
    float* f    = (float*)(ws + off); off += sizeof(float) * (size_t)Lq * 2 * HWq;
    float* f1   = (float*)(ws + off); off += sizeof(float) * (size_t)Lq * MIDq * HWq;
    h8* hA      = (h8*)(ws + off);    off += sizeof(h8) * (size_t)Cq * HWq;
    h8* hB      = (h8*)(ws + off);    off += sizeof(h8) * (size_t)Cq * HWq;
    float* xf   = (float*)(ws + off); off += sizeof(float) * (size_t)Cq * HWq;

    k_conv1<<<Lq * Hq, 256, 0, stream>>>(x, hw1, hb1, f1);
    k_conv2<<<Lq * Hq, 128, 0, stream>>>(f1, hw2, hb2, f);
    k_flow<<<(Lq * HWq + 255) / 256, 256, 0, stream>>>(f, flow);
    k_pack<<<HWq / 256, 256, 0, stream>>>(h0, hA);

    h8* bufs[2] = {hA, hB};
    for (int l = 0; l < Lq; l++) {
        h8* hin = bufs[l & 1];
        h8* hout = bufs[(l + 1) & 1];
        k_warp<<<HWq / 64, 256, 0, stream>>>(hin, hout, flow + (size_t)l * 2 * HWq,
                                             x + (size_t)l * Cq * HWq, listT, l, xf);
        k_apply<<<Hq, 512, 0, stream>>>(xf, sw1, sb1, sw2, sb2,
                                        out + (size_t)l * Cq * HWq);
    }
}